// Round 4
// baseline (393.888 us; speedup 1.0000x reference)
//
#include <hip/hip_runtime.h>
#include <math.h>

typedef unsigned short u16;
typedef __attribute__((ext_vector_type(8))) short short8;
typedef __attribute__((ext_vector_type(4))) float f32x4;

// Problem constants
#define B_   128
#define L_   2048
#define C_   64
#define P_   720
#define P2_  1440
#define NPAD 1536     // proj rows padded to multiple of 128
#define NFFT 4096
#define NROW (B_*C_)  // 8192
#define TCHUNK 16     // time chunks for stats phase 1

// global -> LDS direct staging, 16 B per lane; LDS dest = uniform base + lane*16
#define GLOAD_LDS16(g, l) __builtin_amdgcn_global_load_lds( \
    (const __attribute__((address_space(1))) unsigned int*)(g), \
    (__attribute__((address_space(3))) unsigned int*)(l), 16, 0, 0)

__device__ __forceinline__ u16 f2bf(float f) {
  union { float f; unsigned u; } x; x.f = f;
  unsigned r = x.u + 0x7fffu + ((x.u >> 16) & 1u);
  return (u16)(r >> 16);
}

__device__ __forceinline__ float2 cmul(float2 a, float2 b) {
  return make_float2(a.x * b.x - a.y * b.y, a.x * b.y + a.y * b.x);
}
__device__ __forceinline__ float2 cadd(float2 a, float2 b) { return make_float2(a.x + b.x, a.y + b.y); }
__device__ __forceinline__ float2 csub(float2 a, float2 b) { return make_float2(a.x - b.x, a.y - b.y); }

#define CSWAP(i, j) { float2 tt = a[i]; a[i] = a[j]; a[j] = tt; }

// ===================== 16-point DFT in registers =====================
template<bool INV, bool HZ>
__device__ __forceinline__ void dft16(float2 a[16]) {
  const float S  = INV ? 1.f : -1.f;
  const float c1 = 0.9238795325112867f, s1 = 0.3826834323650898f, q2 = 0.7071067811865476f;
  const float2 W1 = make_float2( c1, S * s1), W2 = make_float2( q2, S * q2), W3 = make_float2( s1, S * c1);
  const float2 W5 = make_float2(-s1, S * c1), W6 = make_float2(-q2, S * q2), W7 = make_float2(-c1, S * s1);
  if (HZ) {
    a[8]  = a[0];
    a[9]  = cmul(a[1], W1);
    a[10] = cmul(a[2], W2);
    a[11] = cmul(a[3], W3);
    a[12] = make_float2(-S * a[4].y, S * a[4].x);
    a[13] = cmul(a[5], W5);
    a[14] = cmul(a[6], W6);
    a[15] = cmul(a[7], W7);
  } else {
    float2 t;
    t = csub(a[0], a[8]);  a[0] = cadd(a[0], a[8]);  a[8]  = t;
    t = csub(a[1], a[9]);  a[1] = cadd(a[1], a[9]);  a[9]  = cmul(t, W1);
    t = csub(a[2], a[10]); a[2] = cadd(a[2], a[10]); a[10] = cmul(t, W2);
    t = csub(a[3], a[11]); a[3] = cadd(a[3], a[11]); a[11] = cmul(t, W3);
    t = csub(a[4], a[12]); a[4] = cadd(a[4], a[12]); a[12] = make_float2(-S * t.y, S * t.x);
    t = csub(a[5], a[13]); a[5] = cadd(a[5], a[13]); a[13] = cmul(t, W5);
    t = csub(a[6], a[14]); a[6] = cadd(a[6], a[14]); a[14] = cmul(t, W6);
    t = csub(a[7], a[15]); a[7] = cadd(a[7], a[15]); a[15] = cmul(t, W7);
  }
#pragma unroll
  for (int h = 0; h < 16; h += 8) {
    float2 t;
    t = csub(a[h+0], a[h+4]); a[h+0] = cadd(a[h+0], a[h+4]); a[h+4] = t;
    t = csub(a[h+1], a[h+5]); a[h+1] = cadd(a[h+1], a[h+5]); a[h+5] = cmul(t, W2);
    t = csub(a[h+2], a[h+6]); a[h+2] = cadd(a[h+2], a[h+6]); a[h+6] = make_float2(-S * t.y, S * t.x);
    t = csub(a[h+3], a[h+7]); a[h+3] = cadd(a[h+3], a[h+7]); a[h+7] = cmul(t, W6);
  }
#pragma unroll
  for (int q = 0; q < 16; q += 4) {
    float2 t;
    t = csub(a[q+0], a[q+2]); a[q+0] = cadd(a[q+0], a[q+2]); a[q+2] = t;
    t = csub(a[q+1], a[q+3]); a[q+1] = cadd(a[q+1], a[q+3]); a[q+3] = make_float2(-S * t.y, S * t.x);
  }
#pragma unroll
  for (int p = 0; p < 16; p += 2) {
    float2 t = csub(a[p], a[p+1]); a[p] = cadd(a[p], a[p+1]); a[p+1] = t;
  }
  CSWAP(1, 8); CSWAP(2, 4); CSWAP(3, 12); CSWAP(5, 10); CSWAP(7, 14); CSWAP(11, 13);
}

// chained twiddle: a[k] *= w1^k, k=1..15
__device__ __forceinline__ void twchain(float2 a[16], float2 w1) {
  float2 cur = w1;
  a[1] = cmul(a[1], cur);
#pragma unroll
  for (int k = 2; k < 16; ++k) { cur = cmul(cur, w1); a[k] = cmul(a[k], cur); }
}

// ===================== swizzled LDS transposes =====================
__device__ __forceinline__ void lds_wA(float2* X, const float2 r[16], int tid) {
  int base = (tid & 15) * 16 + ((tid >> 4) ^ ((tid & 7) << 1));
#pragma unroll
  for (int i = 0; i < 16; ++i) X[base + i * 256] = r[i];
}
__device__ __forceinline__ void lds_wB(float2* X, const float2 r[16], int tid) {
#pragma unroll
  for (int i = 0; i < 16; ++i)
    X[((tid & 0xF0) + i) * 16 + ((tid & 15) ^ ((i & 7) << 1))] = r[i];
}
__device__ __forceinline__ void lds_rd(const float2* X, float2 r[16], int tid) {
  const float4* X4 = (const float4*)X;
#pragma unroll
  for (int p = 0; p < 8; ++p) {
    float4 v = X4[tid * 8 + (p ^ (tid & 7))];
    r[2 * p]     = make_float2(v.x, v.y);
    r[2 * p + 1] = make_float2(v.z, v.w);
  }
}

__device__ __forceinline__ void fft_fwd_hz(float2 r[16], float2* X, int tid, const float2* twg) {
  dft16<false, true>(r);
  twchain(r, twg[tid]);
  lds_wA(X, r, tid);
  __syncthreads();
  lds_rd(X, r, tid);
  dft16<false, false>(r);
  twchain(r, twg[(tid & 15) << 4]);
  __syncthreads();
  lds_wB(X, r, tid);
  __syncthreads();
  lds_rd(X, r, tid);
  dft16<false, false>(r);
}

__device__ __forceinline__ void fft_inv(float2 r[16], float2* X, int tid, const float2* twg) {
  dft16<true, false>(r);
  __syncthreads();
  lds_wB(X, r, tid);
  __syncthreads();
  lds_rd(X, r, tid);
  float2 wb = twg[(tid & 15) << 4];
  twchain(r, make_float2(wb.x, -wb.y));
  dft16<true, false>(r);
  __syncthreads();
  lds_wA(X, r, tid);
  __syncthreads();
  lds_rd(X, r, tid);
  float2 wa = twg[tid];
  twchain(r, make_float2(wa.x, -wa.y));
  dft16<true, false>(r);
}

// ===================== twiddle table =====================
__global__ void k_twfill(float2* __restrict__ tw) {
  int k = threadIdx.x;
  double ang = -2.0 * 3.14159265358979323846 * (double)k / 4096.0;
  tw[k] = make_float2((float)cos(ang), (float)sin(ang));
}

// ===================== proj_w -> bf16, pad 1440 -> 1536 rows =====================
__global__ void k_wconv(const float* __restrict__ pw, u16* __restrict__ wb) {
  size_t idx = (size_t)blockIdx.x * 256 + threadIdx.x;
  int n = (int)(idx >> 11);
  int k = (int)(idx & 2047);
  float v = (n < P2_) ? pw[(size_t)n * L_ + k] : 0.0f;
  wb[idx] = f2bf(v);
}

// ===================== stats phase 1: partial (S,Q) per (b, chunk, c) =====================
__global__ __launch_bounds__(256) void k_stats1(const float* __restrict__ u, float* __restrict__ ps,
                                                float* __restrict__ pq) {
  int blk = blockIdx.x;            // b*TCHUNK + q
  int b = blk >> 4, q = blk & 15;
  int tid = threadIdx.x;
  int c4 = tid & 15, g = tid >> 4; // 16 groups x 8 t-steps
  const float4* u4 = (const float4*)(u + ((size_t)b * L_ + q * 128) * C_);
  float4 s = make_float4(0.f, 0.f, 0.f, 0.f), sq = s;
#pragma unroll
  for (int i = 0; i < 8; ++i) {
    float4 v = u4[(size_t)(g + 16 * i) * 16 + c4];
    s.x += v.x; s.y += v.y; s.z += v.z; s.w += v.w;
    sq.x += v.x * v.x; sq.y += v.y * v.y; sq.z += v.z * v.z; sq.w += v.w * v.w;
  }
  __shared__ float4 sb[16][16], qb[16][16];
  sb[g][c4] = s; qb[g][c4] = sq;
  __syncthreads();
  if (g == 0) {
    float4 S = sb[0][c4], Q = qb[0][c4];
#pragma unroll
    for (int k = 1; k < 16; ++k) {
      float4 a = sb[k][c4], d = qb[k][c4];
      S.x += a.x; S.y += a.y; S.z += a.z; S.w += a.w;
      Q.x += d.x; Q.y += d.y; Q.z += d.z; Q.w += d.w;
    }
    ((float4*)ps)[blk * 16 + c4] = S;
    ((float4*)pq)[blk * 16 + c4] = Q;
  }
}

// ===================== stats phase 2: combine 16 chunks -> mean, std, 1/std =====================
__global__ __launch_bounds__(256) void k_stats2(const float* __restrict__ ps, const float* __restrict__ pq,
                                                float4* __restrict__ mv) {
  int gid = blockIdx.x * 256 + threadIdx.x;   // B_*C_ = 8192
  int b = gid >> 6, c = gid & 63;
  float S = 0.f, Q = 0.f;
#pragma unroll
  for (int q = 0; q < 16; ++q) {
    S += ps[(size_t)(b * 16 + q) * 64 + c];
    Q += pq[(size_t)(b * 16 + q) * 64 + c];
  }
  float mean = S * (1.0f / 2048.0f);
  float var = (Q - S * S * (1.0f / 2048.0f)) * (1.0f / 2047.0f) + 1e-5f;
  float sv = sqrtf(var);
  mv[gid] = make_float4(mean, sv, 1.0f / sv, 0.0f);
}

// ===================== SSM kernels -> kz[j][h] = (K2[h,j], -K[h,j]) =====================
__global__ __launch_bounds__(256) void k_ssmk(const float* __restrict__ Cp, const float* __restrict__ ldt,
                                              const float* __restrict__ lAr, const float* __restrict__ Aim,
                                              float2* __restrict__ kz) {
  int gid = blockIdx.x * 256 + threadIdx.x;   // 64*2048
  int h = gid & 2047;
  int j = gid >> 11;
  float dt = expf(ldt[h]);
  float accx = 0.f;
  float Ar0 = 0.f;
  for (int n = 0; n < 64; ++n) {
    float Ar = -expf(lAr[h * 64 + n]);
    float Ai = Aim[h * 64 + n];
    if (n == 0) Ar0 = Ar;
    float dAr = Ar * dt, dAi = Ai * dt;
    float er = expf(dAr);
    float s1, c1; sincosf(dAi, &s1, &c1);
    float emr = er * c1 - 1.0f, emi = er * s1;
    float inv = 1.0f / (Ar * Ar + Ai * Ai);
    float qr = (emr * Ar + emi * Ai) * inv;
    float qi = (emi * Ar - emr * Ai) * inv;
    float cr = Cp[(size_t)(h * 64 + n) * 2];
    float ci = Cp[(size_t)(h * 64 + n) * 2 + 1];
    float ccr = cr * qr - ci * qi;
    float cci = cr * qi + ci * qr;
    float ej = expf(dAr * (float)j);
    float sj, cj; sincosf(dAi * (float)j, &sj, &cj);
    accx += ccr * (ej * cj) - cci * (ej * sj);
  }
  float K = 2.0f * accx;
  float K2 = 2.0f * K * (Ar0 * (float)j * dt);
  kz[(size_t)j * L_ + h] = make_float2(K2, -K);          // pack K2 - i*K
}

// ===================== normalize + pack (un + i*W) transposed to [row=b*64+c][t] =====================
__global__ __launch_bounds__(256) void k_packT(const float* __restrict__ u, const float* __restrict__ Wn,
                                               const float* __restrict__ lv, const float4* __restrict__ mv,
                                               float2* __restrict__ zu) {
  int b = blockIdx.x >> 5;
  int t0 = (blockIdx.x & 31) << 6;
  int tid = threadIdx.x;
  float stdn = sqrtf(expf(lv[0]));
  __shared__ float2 tile[64][65];
  int c = tid & 63, r = tid >> 6;
  float4 m = mv[b * C_ + c];
#pragma unroll
  for (int i = 0; i < 16; ++i) {
    int t = t0 + i * 4 + r;
    size_t idx = ((size_t)b * L_ + t) * C_ + c;
    float uu = (u[idx] - m.x) * m.z;
    float ww = Wn[idx] * stdn;
    tile[i * 4 + r][c] = make_float2(uu, ww);
  }
  __syncthreads();
  int t = tid & 63, cb = tid >> 6;
#pragma unroll
  for (int i = 0; i < 16; ++i) {
    int c2 = i * 4 + cb;
    zu[((size_t)(b * C_ + c2)) * L_ + t0 + t] = tile[t][c2];
  }
}

// ===================== kernel spectra: G[j] = FFT(K2 - iK)/4096 =====================
__global__ __launch_bounds__(256) void k_fftk(const float2* __restrict__ kz, const float2* __restrict__ twg,
                                              float2* __restrict__ G) {
  __shared__ float2 X[NFFT];
  int j = blockIdx.x, tid = threadIdx.x;
  float2 r[16];
#pragma unroll
  for (int n2 = 0; n2 < 8; ++n2) r[n2] = kz[(size_t)j * L_ + n2 * 256 + tid];
  fft_fwd_hz(r, X, tid, twg);
  const float sc = 1.0f / 4096.0f;
#pragma unroll
  for (int k0 = 0; k0 < 16; ++k0)
    G[(size_t)j * NFFT + k0 * 256 + tid] = make_float2(r[k0].x * sc, r[k0].y * sc);
}

// ===================== main conv per row: y = Re(IFFT(FFT(z) .* G)) + un*D =====================
__global__ __launch_bounds__(256) void k_fftmain(const float2* __restrict__ zu, const float2* __restrict__ twg,
                                                 const float2* __restrict__ G, const float* __restrict__ Dv,
                                                 u16* __restrict__ yT) {
  __shared__ float2 X[NFFT];
  int row = blockIdx.x;           // b*64 + j
  int j = row & 63;
  int tid = threadIdx.x;
  float2 r[16];
  float usav[8];
#pragma unroll
  for (int n2 = 0; n2 < 8; ++n2) {
    r[n2] = zu[(size_t)row * L_ + n2 * 256 + tid];
    usav[n2] = r[n2].x;
  }
  fft_fwd_hz(r, X, tid, twg);
  const float2* Gj = G + (size_t)j * NFFT;
#pragma unroll
  for (int k0 = 0; k0 < 16; ++k0) r[k0] = cmul(r[k0], Gj[k0 * 256 + tid]);
  fft_inv(r, X, tid, twg);
#pragma unroll
  for (int n2 = 8; n2 < 16; ++n2) {
    int t = (n2 - 8) * 256 + tid;
    float yv = r[n2].x + usav[n2 - 8] * Dv[t];
    yT[(size_t)row * L_ + t] = f2bf(yv);
  }
}

// ===================== bf16 MFMA GEMM (m97-style global_load_lds staging) =====================
// z[M=8192][N=1536] = yT[M][K=2048] * Wb[N][K]^T
__global__ __launch_bounds__(256) void k_gemm(const u16* __restrict__ A, const u16* __restrict__ B,
                                              float* __restrict__ Cmat) {
  __shared__ u16 As[128 * 32];
  __shared__ u16 Bs[128 * 32];
  const int K = L_, N = NPAD;
  int tid = threadIdx.x;
  // bijective XCD swizzle: 768 blocks, 96 per XCD
  int bid = blockIdx.x;
  int swz = (bid & 7) * 96 + (bid >> 3);
  int bm = swz % 64, bn = swz / 64;
  int wave = tid >> 6, lane = tid & 63;
  int wm = (wave >> 1) << 6, wn = (wave & 1) << 6;
  int lr = lane & 15, lk = lane >> 4;
  // staging: wave w covers rows [w*32, w*32+32); issue i covers 16 rows.
  // lane l -> row w*32 + i*16 + (l>>2), col (l&3)*8 ; LDS stays linear row-major [128][32].
  int srow = wave * 32 + (lane >> 2);
  int scol = (lane & 3) << 3;
  const u16* Ag = A + (size_t)(bm * 128 + srow) * K + scol;
  const u16* Bg = B + (size_t)(bn * 128 + srow) * K + scol;
  u16* AsB = &As[wave * 32 * 32];
  u16* BsB = &Bs[wave * 32 * 32];
  f32x4 acc[4][4] = {};
  for (int kt = 0; kt < K; kt += 32) {
    __syncthreads();                                   // prev compute done, LDS free
    GLOAD_LDS16(Ag + kt, AsB);
    GLOAD_LDS16(Ag + kt + (size_t)16 * K, AsB + 16 * 32);
    GLOAD_LDS16(Bg + kt, BsB);
    GLOAD_LDS16(Bg + kt + (size_t)16 * K, BsB + 16 * 32);
    __syncthreads();                                   // staging visible (vmcnt drained)
    short8 af[4], bf[4];
#pragma unroll
    for (int i2 = 0; i2 < 4; ++i2) af[i2] = *(const short8*)&As[(wm + i2 * 16 + lr) * 32 + lk * 8];
#pragma unroll
    for (int j2 = 0; j2 < 4; ++j2) bf[j2] = *(const short8*)&Bs[(wn + j2 * 16 + lr) * 32 + lk * 8];
#pragma unroll
    for (int i2 = 0; i2 < 4; ++i2)
#pragma unroll
      for (int j2 = 0; j2 < 4; ++j2)
        acc[i2][j2] = __builtin_amdgcn_mfma_f32_16x16x32_bf16(af[i2], bf[j2], acc[i2][j2], 0, 0, 0);
  }
#pragma unroll
  for (int i2 = 0; i2 < 4; ++i2)
#pragma unroll
    for (int j2 = 0; j2 < 4; ++j2)
#pragma unroll
      for (int r = 0; r < 4; ++r)
        Cmat[(size_t)(bm * 128 + wm + i2 * 16 + lk * 4 + r) * N + bn * 128 + wn + j2 * 16 + lr] =
            acc[i2][j2][r];
}

// ===================== GLU + denorm + transpose to out[b][p][c] =====================
__global__ __launch_bounds__(256) void k_epi(const float* __restrict__ z, const float* __restrict__ pb,
                                             const float4* __restrict__ mv, float* __restrict__ out) {
  int b = blockIdx.x / 23;
  int p0 = (blockIdx.x % 23) * 32;
  int tid = threadIdx.x;
  __shared__ float tile[64][33];
  int pp = tid & 31, ci = tid >> 5;
  for (int cc = ci; cc < 64; cc += 8) {
    int p = p0 + pp;
    float val = 0.f;
    if (p < P_) {
      size_t rowb = (size_t)(b * C_ + cc) * NPAD;
      float a = z[rowb + p] + pb[p];
      float g = z[rowb + P_ + p] + pb[P_ + p];
      float4 m = mv[b * C_ + cc];
      val = a * (1.0f / (1.0f + expf(-g))) * m.y + m.x;
    }
    tile[cc][pp] = val;
  }
  __syncthreads();
  int c2 = tid & 63, pi = tid >> 6;
  for (int q = pi; q < 32; q += 4) {
    int p = p0 + q;
    if (p < P_) out[((size_t)b * P_ + p) * C_ + c2] = tile[c2][q];
  }
}

extern "C" void kernel_launch(void* const* d_in, const int* in_sizes, int n_in,
                              void* d_out, int out_size, void* d_ws, size_t ws_size,
                              hipStream_t stream) {
  const float* u   = (const float*)d_in[0];
  const float* Wn  = (const float*)d_in[4];
  const float* Dv  = (const float*)d_in[5];
  const float* lv  = (const float*)d_in[6];
  const float* Cp  = (const float*)d_in[7];
  const float* ldt = (const float*)d_in[8];
  const float* lAr = (const float*)d_in[9];
  const float* Aim = (const float*)d_in[10];
  const float* pw  = (const float*)d_in[11];
  const float* pb  = (const float*)d_in[12];
  float* out = (float*)d_out;
  char* ws = (char*)d_ws;

  // workspace layout (bytes)
  float2* tw = (float2*)(ws + 0);                  // 2 KB
  float4* mv = (float4*)(ws + (64 << 10));         // 128 KB  -> ends 192 KB
  float2* G  = (float2*)(ws + (1 << 20));          // 2 MB    -> ends 3 MB
  float2* kz = (float2*)(ws + (3 << 20));          // 1 MB    -> ends 4 MB
  u16*    Wb = (u16*)   (ws + (4 << 20));          // 6 MB    -> ends 10 MB
  float*  ps = (float*) (ws + (10 << 20));         // 512 KB
  float*  pq = (float*) (ws + (10 << 20) + (512 << 10)); // 512 KB -> ends 11 MB
  u16*    yT = (u16*)   (ws + (16 << 20));         // 32 MB   -> ends 48 MB
  float2* zu = (float2*)(ws + ((size_t)48 << 20)); // 128 MB  -> ends 176 MB
  float*  zz = (float*) (ws + ((size_t)48 << 20)); // 48 MB, aliases zu (zu dead before GEMM)

  k_twfill<<<1, 256, 0, stream>>>(tw);
  k_wconv<<<(NPAD * L_) / 256, 256, 0, stream>>>(pw, Wb);
  k_stats1<<<B_ * TCHUNK, 256, 0, stream>>>(u, ps, pq);
  k_stats2<<<(B_ * C_) / 256, 256, 0, stream>>>(ps, pq, mv);
  k_ssmk<<<(C_ * L_) / 256, 256, 0, stream>>>(Cp, ldt, lAr, Aim, kz);
  k_packT<<<B_ * (L_ / 64), 256, 0, stream>>>(u, Wn, lv, mv, zu);
  k_fftk<<<C_, 256, 0, stream>>>(kz, tw, G);
  k_fftmain<<<NROW, 256, 0, stream>>>(zu, tw, G, Dv, yT);
  k_gemm<<<64 * (NPAD / 128), 256, 0, stream>>>(yT, Wb, zz);
  k_epi<<<B_ * 23, 256, 0, stream>>>(zz, pb, mv, out);
}

// Round 5
// 369.673 us; speedup vs baseline: 1.0655x; 1.0655x over previous
//
#include <hip/hip_runtime.h>
#include <math.h>

typedef unsigned short u16;
typedef __attribute__((ext_vector_type(8))) short short8;
typedef __attribute__((ext_vector_type(4))) float f32x4;

// Problem constants
#define B_   128
#define L_   2048
#define C_   64
#define P_   720
#define P2_  1440
#define NPAD 1536     // proj rows padded to multiple of 128
#define NFFT 4096
#define NROW (B_*C_)  // 8192
#define TCHUNK 16     // time chunks for stats phase 1

// global -> LDS direct staging, 16 B per lane; LDS dest = uniform base + lane*16
#define GLOAD_LDS16(g, l) __builtin_amdgcn_global_load_lds( \
    (const __attribute__((address_space(1))) unsigned int*)(g), \
    (__attribute__((address_space(3))) unsigned int*)(l), 16, 0, 0)

__device__ __forceinline__ u16 f2bf(float f) {
  union { float f; unsigned u; } x; x.f = f;
  unsigned r = x.u + 0x7fffu + ((x.u >> 16) & 1u);
  return (u16)(r >> 16);
}

__device__ __forceinline__ float2 cmul(float2 a, float2 b) {
  return make_float2(a.x * b.x - a.y * b.y, a.x * b.y + a.y * b.x);
}
__device__ __forceinline__ float2 cadd(float2 a, float2 b) { return make_float2(a.x + b.x, a.y + b.y); }
__device__ __forceinline__ float2 csub(float2 a, float2 b) { return make_float2(a.x - b.x, a.y - b.y); }

#define CSWAP(i, j) { float2 tt = a[i]; a[i] = a[j]; a[j] = tt; }

// ===================== 16-point DFT in registers =====================
template<bool INV, bool HZ>
__device__ __forceinline__ void dft16(float2 a[16]) {
  const float S  = INV ? 1.f : -1.f;
  const float c1 = 0.9238795325112867f, s1 = 0.3826834323650898f, q2 = 0.7071067811865476f;
  const float2 W1 = make_float2( c1, S * s1), W2 = make_float2( q2, S * q2), W3 = make_float2( s1, S * c1);
  const float2 W5 = make_float2(-s1, S * c1), W6 = make_float2(-q2, S * q2), W7 = make_float2(-c1, S * s1);
  if (HZ) {
    a[8]  = a[0];
    a[9]  = cmul(a[1], W1);
    a[10] = cmul(a[2], W2);
    a[11] = cmul(a[3], W3);
    a[12] = make_float2(-S * a[4].y, S * a[4].x);
    a[13] = cmul(a[5], W5);
    a[14] = cmul(a[6], W6);
    a[15] = cmul(a[7], W7);
  } else {
    float2 t;
    t = csub(a[0], a[8]);  a[0] = cadd(a[0], a[8]);  a[8]  = t;
    t = csub(a[1], a[9]);  a[1] = cadd(a[1], a[9]);  a[9]  = cmul(t, W1);
    t = csub(a[2], a[10]); a[2] = cadd(a[2], a[10]); a[10] = cmul(t, W2);
    t = csub(a[3], a[11]); a[3] = cadd(a[3], a[11]); a[11] = cmul(t, W3);
    t = csub(a[4], a[12]); a[4] = cadd(a[4], a[12]); a[12] = make_float2(-S * t.y, S * t.x);
    t = csub(a[5], a[13]); a[5] = cadd(a[5], a[13]); a[13] = cmul(t, W5);
    t = csub(a[6], a[14]); a[6] = cadd(a[6], a[14]); a[14] = cmul(t, W6);
    t = csub(a[7], a[15]); a[7] = cadd(a[7], a[15]); a[15] = cmul(t, W7);
  }
#pragma unroll
  for (int h = 0; h < 16; h += 8) {
    float2 t;
    t = csub(a[h+0], a[h+4]); a[h+0] = cadd(a[h+0], a[h+4]); a[h+4] = t;
    t = csub(a[h+1], a[h+5]); a[h+1] = cadd(a[h+1], a[h+5]); a[h+5] = cmul(t, W2);
    t = csub(a[h+2], a[h+6]); a[h+2] = cadd(a[h+2], a[h+6]); a[h+6] = make_float2(-S * t.y, S * t.x);
    t = csub(a[h+3], a[h+7]); a[h+3] = cadd(a[h+3], a[h+7]); a[h+7] = cmul(t, W6);
  }
#pragma unroll
  for (int q = 0; q < 16; q += 4) {
    float2 t;
    t = csub(a[q+0], a[q+2]); a[q+0] = cadd(a[q+0], a[q+2]); a[q+2] = t;
    t = csub(a[q+1], a[q+3]); a[q+1] = cadd(a[q+1], a[q+3]); a[q+3] = make_float2(-S * t.y, S * t.x);
  }
#pragma unroll
  for (int p = 0; p < 16; p += 2) {
    float2 t = csub(a[p], a[p+1]); a[p] = cadd(a[p], a[p+1]); a[p+1] = t;
  }
  CSWAP(1, 8); CSWAP(2, 4); CSWAP(3, 12); CSWAP(5, 10); CSWAP(7, 14); CSWAP(11, 13);
}

// chained twiddle: a[k] *= w1^k, k=1..15
__device__ __forceinline__ void twchain(float2 a[16], float2 w1) {
  float2 cur = w1;
  a[1] = cmul(a[1], cur);
#pragma unroll
  for (int k = 2; k < 16; ++k) { cur = cmul(cur, w1); a[k] = cmul(a[k], cur); }
}

// ===================== swizzled LDS transposes =====================
__device__ __forceinline__ void lds_wA(float2* X, const float2 r[16], int tid) {
  int base = (tid & 15) * 16 + ((tid >> 4) ^ ((tid & 7) << 1));
#pragma unroll
  for (int i = 0; i < 16; ++i) X[base + i * 256] = r[i];
}
__device__ __forceinline__ void lds_wB(float2* X, const float2 r[16], int tid) {
#pragma unroll
  for (int i = 0; i < 16; ++i)
    X[((tid & 0xF0) + i) * 16 + ((tid & 15) ^ ((i & 7) << 1))] = r[i];
}
__device__ __forceinline__ void lds_rd(const float2* X, float2 r[16], int tid) {
  const float4* X4 = (const float4*)X;
#pragma unroll
  for (int p = 0; p < 8; ++p) {
    float4 v = X4[tid * 8 + (p ^ (tid & 7))];
    r[2 * p]     = make_float2(v.x, v.y);
    r[2 * p + 1] = make_float2(v.z, v.w);
  }
}

__device__ __forceinline__ void fft_fwd_hz(float2 r[16], float2* X, int tid, const float2* twg) {
  dft16<false, true>(r);
  twchain(r, twg[tid]);
  lds_wA(X, r, tid);
  __syncthreads();
  lds_rd(X, r, tid);
  dft16<false, false>(r);
  twchain(r, twg[(tid & 15) << 4]);
  __syncthreads();
  lds_wB(X, r, tid);
  __syncthreads();
  lds_rd(X, r, tid);
  dft16<false, false>(r);
}

__device__ __forceinline__ void fft_inv(float2 r[16], float2* X, int tid, const float2* twg) {
  dft16<true, false>(r);
  __syncthreads();
  lds_wB(X, r, tid);
  __syncthreads();
  lds_rd(X, r, tid);
  float2 wb = twg[(tid & 15) << 4];
  twchain(r, make_float2(wb.x, -wb.y));
  dft16<true, false>(r);
  __syncthreads();
  lds_wA(X, r, tid);
  __syncthreads();
  lds_rd(X, r, tid);
  float2 wa = twg[tid];
  twchain(r, make_float2(wa.x, -wa.y));
  dft16<true, false>(r);
}

// ===================== twiddle table =====================
__global__ void k_twfill(float2* __restrict__ tw) {
  int k = threadIdx.x;
  double ang = -2.0 * 3.14159265358979323846 * (double)k / 4096.0;
  tw[k] = make_float2((float)cos(ang), (float)sin(ang));
}

// ===================== proj_w -> bf16, pad 1440 -> 1536 rows =====================
__global__ void k_wconv(const float* __restrict__ pw, u16* __restrict__ wb) {
  size_t idx = (size_t)blockIdx.x * 256 + threadIdx.x;
  int n = (int)(idx >> 11);
  int k = (int)(idx & 2047);
  float v = (n < P2_) ? pw[(size_t)n * L_ + k] : 0.0f;
  wb[idx] = f2bf(v);
}

// ===================== stats phase 1: partial (S,Q) per (b, chunk, c) =====================
__global__ __launch_bounds__(256) void k_stats1(const float* __restrict__ u, float* __restrict__ ps,
                                                float* __restrict__ pq) {
  int blk = blockIdx.x;            // b*TCHUNK + q
  int b = blk >> 4, q = blk & 15;
  int tid = threadIdx.x;
  int c4 = tid & 15, g = tid >> 4; // 16 groups x 8 t-steps
  const float4* u4 = (const float4*)(u + ((size_t)b * L_ + q * 128) * C_);
  float4 s = make_float4(0.f, 0.f, 0.f, 0.f), sq = s;
#pragma unroll
  for (int i = 0; i < 8; ++i) {
    float4 v = u4[(size_t)(g + 16 * i) * 16 + c4];
    s.x += v.x; s.y += v.y; s.z += v.z; s.w += v.w;
    sq.x += v.x * v.x; sq.y += v.y * v.y; sq.z += v.z * v.z; sq.w += v.w * v.w;
  }
  __shared__ float4 sb[16][16], qb[16][16];
  sb[g][c4] = s; qb[g][c4] = sq;
  __syncthreads();
  if (g == 0) {
    float4 S = sb[0][c4], Q = qb[0][c4];
#pragma unroll
    for (int k = 1; k < 16; ++k) {
      float4 a = sb[k][c4], d = qb[k][c4];
      S.x += a.x; S.y += a.y; S.z += a.z; S.w += a.w;
      Q.x += d.x; Q.y += d.y; Q.z += d.z; Q.w += d.w;
    }
    ((float4*)ps)[blk * 16 + c4] = S;
    ((float4*)pq)[blk * 16 + c4] = Q;
  }
}

// ===================== stats phase 2: combine 16 chunks -> mean, std, 1/std =====================
__global__ __launch_bounds__(256) void k_stats2(const float* __restrict__ ps, const float* __restrict__ pq,
                                                float4* __restrict__ mv) {
  int gid = blockIdx.x * 256 + threadIdx.x;   // B_*C_ = 8192
  int b = gid >> 6, c = gid & 63;
  float S = 0.f, Q = 0.f;
#pragma unroll
  for (int q = 0; q < 16; ++q) {
    S += ps[(size_t)(b * 16 + q) * 64 + c];
    Q += pq[(size_t)(b * 16 + q) * 64 + c];
  }
  float mean = S * (1.0f / 2048.0f);
  float var = (Q - S * S * (1.0f / 2048.0f)) * (1.0f / 2047.0f) + 1e-5f;
  float sv = sqrtf(var);
  mv[gid] = make_float4(mean, sv, 1.0f / sv, 0.0f);
}

// ===================== SSM kernels -> kz[j][h] = (K2[h,j], -K[h,j]) =====================
__global__ __launch_bounds__(256) void k_ssmk(const float* __restrict__ Cp, const float* __restrict__ ldt,
                                              const float* __restrict__ lAr, const float* __restrict__ Aim,
                                              float2* __restrict__ kz) {
  int gid = blockIdx.x * 256 + threadIdx.x;   // 64*2048
  int h = gid & 2047;
  int j = gid >> 11;
  float dt = expf(ldt[h]);
  float accx = 0.f;
  float Ar0 = 0.f;
  for (int n = 0; n < 64; ++n) {
    float Ar = -expf(lAr[h * 64 + n]);
    float Ai = Aim[h * 64 + n];
    if (n == 0) Ar0 = Ar;
    float dAr = Ar * dt, dAi = Ai * dt;
    float er = expf(dAr);
    float s1, c1; sincosf(dAi, &s1, &c1);
    float emr = er * c1 - 1.0f, emi = er * s1;
    float inv = 1.0f / (Ar * Ar + Ai * Ai);
    float qr = (emr * Ar + emi * Ai) * inv;
    float qi = (emi * Ar - emr * Ai) * inv;
    float cr = Cp[(size_t)(h * 64 + n) * 2];
    float ci = Cp[(size_t)(h * 64 + n) * 2 + 1];
    float ccr = cr * qr - ci * qi;
    float cci = cr * qi + ci * qr;
    float ej = expf(dAr * (float)j);
    float sj, cj; sincosf(dAi * (float)j, &sj, &cj);
    accx += ccr * (ej * cj) - cci * (ej * sj);
  }
  float K = 2.0f * accx;
  float K2 = 2.0f * K * (Ar0 * (float)j * dt);
  kz[(size_t)j * L_ + h] = make_float2(K2, -K);          // pack K2 - i*K
}

// ===================== normalize + pack (un + i*W) transposed to [row=b*64+c][t] =====================
__global__ __launch_bounds__(256) void k_packT(const float* __restrict__ u, const float* __restrict__ Wn,
                                               const float* __restrict__ lv, const float4* __restrict__ mv,
                                               float2* __restrict__ zu) {
  int b = blockIdx.x >> 5;
  int t0 = (blockIdx.x & 31) << 6;
  int tid = threadIdx.x;
  float stdn = sqrtf(expf(lv[0]));
  __shared__ float2 tile[64][65];
  int c = tid & 63, r = tid >> 6;
  float4 m = mv[b * C_ + c];
#pragma unroll
  for (int i = 0; i < 16; ++i) {
    int t = t0 + i * 4 + r;
    size_t idx = ((size_t)b * L_ + t) * C_ + c;
    float uu = (u[idx] - m.x) * m.z;
    float ww = Wn[idx] * stdn;
    tile[i * 4 + r][c] = make_float2(uu, ww);
  }
  __syncthreads();
  int t = tid & 63, cb = tid >> 6;
#pragma unroll
  for (int i = 0; i < 16; ++i) {
    int c2 = i * 4 + cb;
    zu[((size_t)(b * C_ + c2)) * L_ + t0 + t] = tile[t][c2];
  }
}

// ===================== kernel spectra: G[j] = FFT(K2 - iK)/4096 =====================
__global__ __launch_bounds__(256) void k_fftk(const float2* __restrict__ kz, const float2* __restrict__ twg,
                                              float2* __restrict__ G) {
  __shared__ float2 X[NFFT];
  int j = blockIdx.x, tid = threadIdx.x;
  float2 r[16];
#pragma unroll
  for (int n2 = 0; n2 < 8; ++n2) r[n2] = kz[(size_t)j * L_ + n2 * 256 + tid];
  fft_fwd_hz(r, X, tid, twg);
  const float sc = 1.0f / 4096.0f;
#pragma unroll
  for (int k0 = 0; k0 < 16; ++k0)
    G[(size_t)j * NFFT + k0 * 256 + tid] = make_float2(r[k0].x * sc, r[k0].y * sc);
}

// ===================== main conv per row: y = Re(IFFT(FFT(z) .* G)) + un*D =====================
__global__ __launch_bounds__(256) void k_fftmain(const float2* __restrict__ zu, const float2* __restrict__ twg,
                                                 const float2* __restrict__ G, const float* __restrict__ Dv,
                                                 u16* __restrict__ yT) {
  __shared__ float2 X[NFFT];
  int row = blockIdx.x;           // b*64 + j
  int j = row & 63;
  int tid = threadIdx.x;
  float2 r[16];
  float usav[8];
#pragma unroll
  for (int n2 = 0; n2 < 8; ++n2) {
    r[n2] = zu[(size_t)row * L_ + n2 * 256 + tid];
    usav[n2] = r[n2].x;
  }
  fft_fwd_hz(r, X, tid, twg);
  const float2* Gj = G + (size_t)j * NFFT;
#pragma unroll
  for (int k0 = 0; k0 < 16; ++k0) r[k0] = cmul(r[k0], Gj[k0 * 256 + tid]);
  fft_inv(r, X, tid, twg);
#pragma unroll
  for (int n2 = 8; n2 < 16; ++n2) {
    int t = (n2 - 8) * 256 + tid;
    float yv = r[n2].x + usav[n2 - 8] * Dv[t];
    yT[(size_t)row * L_ + t] = f2bf(yv);
  }
}

// ===================== bf16 MFMA GEMM — 2-phase template (T3 minimum): =====================
// dbuf LDS, 1 barrier/iter, stage-next-first via global_load_lds.
// z[M=8192][N=1536] = yT[M][K=2048] * Wb[N][K]^T
__global__ __launch_bounds__(256) void k_gemm(const u16* __restrict__ A, const u16* __restrict__ B,
                                              float* __restrict__ Cmat) {
  __shared__ u16 As[2][128 * 32];
  __shared__ u16 Bs[2][128 * 32];
  const int K = L_, N = NPAD;
  int tid = threadIdx.x;
  // bijective XCD swizzle: 768 blocks, 96 per XCD
  int bid = blockIdx.x;
  int swz = (bid & 7) * 96 + (bid >> 3);
  int bm = swz % 64, bn = swz / 64;
  int wave = tid >> 6, lane = tid & 63;
  int wm = (wave >> 1) << 6, wn = (wave & 1) << 6;
  int lr = lane & 15, lk = lane >> 4;
  // staging: wave w covers rows [w*32, w*32+32); each issue = 16 rows x 32 cols = 1024 B.
  // lane l -> row w*32 + i*16 + (l>>2), col (l&3)*8 ; LDS linear row-major [128][32].
  int srow = wave * 32 + (lane >> 2);
  int scol = (lane & 3) << 3;
  const u16* Ag = A + (size_t)(bm * 128 + srow) * K + scol;
  const u16* Bg = B + (size_t)(bn * 128 + srow) * K + scol;
  int woff = wave * 32 * 32;
  f32x4 acc[4][4] = {};
  // prologue: stage tile 0 into buffer 0
  GLOAD_LDS16(Ag, &As[0][woff]);
  GLOAD_LDS16(Ag + (size_t)16 * K, &As[0][woff + 16 * 32]);
  GLOAD_LDS16(Bg, &Bs[0][woff]);
  GLOAD_LDS16(Bg + (size_t)16 * K, &Bs[0][woff + 16 * 32]);
  int cur = 0;
  for (int kt = 0; kt < K; kt += 32) {
    __syncthreads();     // compiler emits vmcnt(0) lgkmcnt(0) before s_barrier:
                         // drains the stage issued LAST iter -> buf[cur] ready,
                         // and prev iter's ds_reads done -> buf[cur^1] free.
    if (kt + 32 < K) {   // stage NEXT tile first (overlaps with ds_read + MFMA below)
      GLOAD_LDS16(Ag + kt + 32, &As[cur ^ 1][woff]);
      GLOAD_LDS16(Ag + kt + 32 + (size_t)16 * K, &As[cur ^ 1][woff + 16 * 32]);
      GLOAD_LDS16(Bg + kt + 32, &Bs[cur ^ 1][woff]);
      GLOAD_LDS16(Bg + kt + 32 + (size_t)16 * K, &Bs[cur ^ 1][woff + 16 * 32]);
    }
    short8 af[4], bf[4];
#pragma unroll
    for (int i2 = 0; i2 < 4; ++i2) af[i2] = *(const short8*)&As[cur][(wm + i2 * 16 + lr) * 32 + lk * 8];
#pragma unroll
    for (int j2 = 0; j2 < 4; ++j2) bf[j2] = *(const short8*)&Bs[cur][(wn + j2 * 16 + lr) * 32 + lk * 8];
#pragma unroll
    for (int i2 = 0; i2 < 4; ++i2)
#pragma unroll
      for (int j2 = 0; j2 < 4; ++j2)
        acc[i2][j2] = __builtin_amdgcn_mfma_f32_16x16x32_bf16(af[i2], bf[j2], acc[i2][j2], 0, 0, 0);
    cur ^= 1;
  }
#pragma unroll
  for (int i2 = 0; i2 < 4; ++i2)
#pragma unroll
    for (int j2 = 0; j2 < 4; ++j2)
#pragma unroll
      for (int r = 0; r < 4; ++r)
        Cmat[(size_t)(bm * 128 + wm + i2 * 16 + lk * 4 + r) * N + bn * 128 + wn + j2 * 16 + lr] =
            acc[i2][j2][r];
}

// ===================== GLU + denorm + transpose to out[b][p][c] =====================
__global__ __launch_bounds__(256) void k_epi(const float* __restrict__ z, const float* __restrict__ pb,
                                             const float4* __restrict__ mv, float* __restrict__ out) {
  int b = blockIdx.x / 23;
  int p0 = (blockIdx.x % 23) * 32;
  int tid = threadIdx.x;
  __shared__ float tile[64][33];
  int pp = tid & 31, ci = tid >> 5;
  for (int cc = ci; cc < 64; cc += 8) {
    int p = p0 + pp;
    float val = 0.f;
    if (p < P_) {
      size_t rowb = (size_t)(b * C_ + cc) * NPAD;
      float a = z[rowb + p] + pb[p];
      float g = z[rowb + P_ + p] + pb[P_ + p];
      float4 m = mv[b * C_ + cc];
      val = a * (1.0f / (1.0f + expf(-g))) * m.y + m.x;
    }
    tile[cc][pp] = val;
  }
  __syncthreads();
  int c2 = tid & 63, pi = tid >> 6;
  for (int q = pi; q < 32; q += 4) {
    int p = p0 + q;
    if (p < P_) out[((size_t)b * P_ + p) * C_ + c2] = tile[c2][q];
  }
}

extern "C" void kernel_launch(void* const* d_in, const int* in_sizes, int n_in,
                              void* d_out, int out_size, void* d_ws, size_t ws_size,
                              hipStream_t stream) {
  const float* u   = (const float*)d_in[0];
  const float* Wn  = (const float*)d_in[4];
  const float* Dv  = (const float*)d_in[5];
  const float* lv  = (const float*)d_in[6];
  const float* Cp  = (const float*)d_in[7];
  const float* ldt = (const float*)d_in[8];
  const float* lAr = (const float*)d_in[9];
  const float* Aim = (const float*)d_in[10];
  const float* pw  = (const float*)d_in[11];
  const float* pb  = (const float*)d_in[12];
  float* out = (float*)d_out;
  char* ws = (char*)d_ws;

  // workspace layout (bytes)
  float2* tw = (float2*)(ws + 0);                  // 2 KB
  float4* mv = (float4*)(ws + (64 << 10));         // 128 KB  -> ends 192 KB
  float2* G  = (float2*)(ws + (1 << 20));          // 2 MB    -> ends 3 MB
  float2* kz = (float2*)(ws + (3 << 20));          // 1 MB    -> ends 4 MB
  u16*    Wb = (u16*)   (ws + (4 << 20));          // 6 MB    -> ends 10 MB
  float*  ps = (float*) (ws + (10 << 20));         // 512 KB
  float*  pq = (float*) (ws + (10 << 20) + (512 << 10)); // 512 KB -> ends 11 MB
  u16*    yT = (u16*)   (ws + (16 << 20));         // 32 MB   -> ends 48 MB
  float2* zu = (float2*)(ws + ((size_t)48 << 20)); // 128 MB  -> ends 176 MB
  float*  zz = (float*) (ws + ((size_t)48 << 20)); // 48 MB, aliases zu (zu dead before GEMM)

  k_twfill<<<1, 256, 0, stream>>>(tw);
  k_wconv<<<(NPAD * L_) / 256, 256, 0, stream>>>(pw, Wb);
  k_stats1<<<B_ * TCHUNK, 256, 0, stream>>>(u, ps, pq);
  k_stats2<<<(B_ * C_) / 256, 256, 0, stream>>>(ps, pq, mv);
  k_ssmk<<<(C_ * L_) / 256, 256, 0, stream>>>(Cp, ldt, lAr, Aim, kz);
  k_packT<<<B_ * (L_ / 64), 256, 0, stream>>>(u, Wn, lv, mv, zu);
  k_fftk<<<C_, 256, 0, stream>>>(kz, tw, G);
  k_fftmain<<<NROW, 256, 0, stream>>>(zu, tw, G, Dv, yT);
  k_gemm<<<64 * (NPAD / 128), 256, 0, stream>>>(yT, Wb, zz);
  k_epi<<<B_ * 23, 256, 0, stream>>>(zz, pb, mv, out);
}

// Round 7
// 353.093 us; speedup vs baseline: 1.1155x; 1.0470x over previous
//
#include <hip/hip_runtime.h>
#include <math.h>

typedef unsigned short u16;
typedef unsigned int u32;
typedef __attribute__((ext_vector_type(8))) short short8;
typedef __attribute__((ext_vector_type(4))) float f32x4;

// Problem constants
#define B_   128
#define L_   2048
#define C_   64
#define P_   720
#define P2_  1440
#define NPAD 1536     // proj rows padded to multiple of 128
#define NFFT 4096
#define NROW (B_*C_)  // 8192
#define TCHUNK 16     // time chunks for stats phase 1

__device__ __forceinline__ u16 f2bf(float f) {
  union { float f; unsigned u; } x; x.f = f;
  unsigned r = x.u + 0x7fffu + ((x.u >> 16) & 1u);
  return (u16)(r >> 16);
}
__device__ __forceinline__ float bf2f_lo(u32 v) {
  union { unsigned u; float f; } x; x.u = v << 16; return x.f;
}
__device__ __forceinline__ float bf2f_hi(u32 v) {
  union { unsigned u; float f; } x; x.u = v & 0xffff0000u; return x.f;
}

__device__ __forceinline__ float2 cmul(float2 a, float2 b) {
  return make_float2(a.x * b.x - a.y * b.y, a.x * b.y + a.y * b.x);
}
__device__ __forceinline__ float2 cadd(float2 a, float2 b) { return make_float2(a.x + b.x, a.y + b.y); }
__device__ __forceinline__ float2 csub(float2 a, float2 b) { return make_float2(a.x - b.x, a.y - b.y); }

#define CSWAP(i, j) { float2 tt = a[i]; a[i] = a[j]; a[j] = tt; }

// ===================== 16-point DFT in registers =====================
template<bool INV, bool HZ>
__device__ __forceinline__ void dft16(float2 a[16]) {
  const float S  = INV ? 1.f : -1.f;
  const float c1 = 0.9238795325112867f, s1 = 0.3826834323650898f, q2 = 0.7071067811865476f;
  const float2 W1 = make_float2( c1, S * s1), W2 = make_float2( q2, S * q2), W3 = make_float2( s1, S * c1);
  const float2 W5 = make_float2(-s1, S * c1), W6 = make_float2(-q2, S * q2), W7 = make_float2(-c1, S * s1);
  if (HZ) {
    a[8]  = a[0];
    a[9]  = cmul(a[1], W1);
    a[10] = cmul(a[2], W2);
    a[11] = cmul(a[3], W3);
    a[12] = make_float2(-S * a[4].y, S * a[4].x);
    a[13] = cmul(a[5], W5);
    a[14] = cmul(a[6], W6);
    a[15] = cmul(a[7], W7);
  } else {
    float2 t;
    t = csub(a[0], a[8]);  a[0] = cadd(a[0], a[8]);  a[8]  = t;
    t = csub(a[1], a[9]);  a[1] = cadd(a[1], a[9]);  a[9]  = cmul(t, W1);
    t = csub(a[2], a[10]); a[2] = cadd(a[2], a[10]); a[10] = cmul(t, W2);
    t = csub(a[3], a[11]); a[3] = cadd(a[3], a[11]); a[11] = cmul(t, W3);
    t = csub(a[4], a[12]); a[4] = cadd(a[4], a[12]); a[12] = make_float2(-S * t.y, S * t.x);
    t = csub(a[5], a[13]); a[5] = cadd(a[5], a[13]); a[13] = cmul(t, W5);
    t = csub(a[6], a[14]); a[6] = cadd(a[6], a[14]); a[14] = cmul(t, W6);
    t = csub(a[7], a[15]); a[7] = cadd(a[7], a[15]); a[15] = cmul(t, W7);
  }
#pragma unroll
  for (int h = 0; h < 16; h += 8) {
    float2 t;
    t = csub(a[h+0], a[h+4]); a[h+0] = cadd(a[h+0], a[h+4]); a[h+4] = t;
    t = csub(a[h+1], a[h+5]); a[h+1] = cadd(a[h+1], a[h+5]); a[h+5] = cmul(t, W2);
    t = csub(a[h+2], a[h+6]); a[h+2] = cadd(a[h+2], a[h+6]); a[h+6] = make_float2(-S * t.y, S * t.x);
    t = csub(a[h+3], a[h+7]); a[h+3] = cadd(a[h+3], a[h+7]); a[h+7] = cmul(t, W6);
  }
#pragma unroll
  for (int q = 0; q < 16; q += 4) {
    float2 t;
    t = csub(a[q+0], a[q+2]); a[q+0] = cadd(a[q+0], a[q+2]); a[q+2] = t;
    t = csub(a[q+1], a[q+3]); a[q+1] = cadd(a[q+1], a[q+3]); a[q+3] = make_float2(-S * t.y, S * t.x);
  }
#pragma unroll
  for (int p = 0; p < 16; p += 2) {
    float2 t = csub(a[p], a[p+1]); a[p] = cadd(a[p], a[p+1]); a[p+1] = t;
  }
  CSWAP(1, 8); CSWAP(2, 4); CSWAP(3, 12); CSWAP(5, 10); CSWAP(7, 14); CSWAP(11, 13);
}

// twiddle apply: a[k] *= w1^k. Powers via binary tree (depth 4) -> independent applies (ILP).
__device__ __forceinline__ void twchain(float2 a[16], float2 w1) {
  float2 w2 = cmul(w1, w1);
  float2 w3 = cmul(w2, w1);
  float2 w4 = cmul(w2, w2);
  float2 w5 = cmul(w3, w2);
  float2 w6 = cmul(w3, w3);
  float2 w7 = cmul(w4, w3);
  float2 w8 = cmul(w4, w4);
  float2 w9 = cmul(w5, w4);
  float2 w10 = cmul(w5, w5);
  float2 w11 = cmul(w6, w5);
  float2 w12 = cmul(w6, w6);
  float2 w13 = cmul(w7, w6);
  float2 w14 = cmul(w7, w7);
  float2 w15 = cmul(w8, w7);
  a[1]  = cmul(a[1],  w1);  a[2]  = cmul(a[2],  w2);  a[3]  = cmul(a[3],  w3);
  a[4]  = cmul(a[4],  w4);  a[5]  = cmul(a[5],  w5);  a[6]  = cmul(a[6],  w6);
  a[7]  = cmul(a[7],  w7);  a[8]  = cmul(a[8],  w8);  a[9]  = cmul(a[9],  w9);
  a[10] = cmul(a[10], w10); a[11] = cmul(a[11], w11); a[12] = cmul(a[12], w12);
  a[13] = cmul(a[13], w13); a[14] = cmul(a[14], w14); a[15] = cmul(a[15], w15);
}

// ===================== swizzled LDS transposes =====================
__device__ __forceinline__ void lds_wA(float2* X, const float2 r[16], int tid) {
  int base = (tid & 15) * 16 + ((tid >> 4) ^ ((tid & 7) << 1));
#pragma unroll
  for (int i = 0; i < 16; ++i) X[base + i * 256] = r[i];
}
__device__ __forceinline__ void lds_wB(float2* X, const float2 r[16], int tid) {
#pragma unroll
  for (int i = 0; i < 16; ++i)
    X[((tid & 0xF0) + i) * 16 + ((tid & 15) ^ ((i & 7) << 1))] = r[i];
}
__device__ __forceinline__ void lds_rd(const float2* X, float2 r[16], int tid) {
  const float4* X4 = (const float4*)X;
#pragma unroll
  for (int p = 0; p < 8; ++p) {
    float4 v = X4[tid * 8 + (p ^ (tid & 7))];
    r[2 * p]     = make_float2(v.x, v.y);
    r[2 * p + 1] = make_float2(v.z, v.w);
  }
}

__device__ __forceinline__ void fft_fwd_hz(float2 r[16], float2* X, int tid, const float2* twg) {
  dft16<false, true>(r);
  twchain(r, twg[tid]);
  lds_wA(X, r, tid);
  __syncthreads();
  lds_rd(X, r, tid);
  dft16<false, false>(r);
  twchain(r, twg[(tid & 15) << 4]);
  __syncthreads();
  lds_wB(X, r, tid);
  __syncthreads();
  lds_rd(X, r, tid);
  dft16<false, false>(r);
}

__device__ __forceinline__ void fft_inv(float2 r[16], float2* X, int tid, const float2* twg) {
  dft16<true, false>(r);
  __syncthreads();
  lds_wB(X, r, tid);
  __syncthreads();
  lds_rd(X, r, tid);
  float2 wb = twg[(tid & 15) << 4];
  twchain(r, make_float2(wb.x, -wb.y));
  dft16<true, false>(r);
  __syncthreads();
  lds_wA(X, r, tid);
  __syncthreads();
  lds_rd(X, r, tid);
  float2 wa = twg[tid];
  twchain(r, make_float2(wa.x, -wa.y));
  dft16<true, false>(r);
}

// ===================== twiddle table =====================
__global__ void k_twfill(float2* __restrict__ tw) {
  int k = threadIdx.x;
  double ang = -2.0 * 3.14159265358979323846 * (double)k / 4096.0;
  tw[k] = make_float2((float)cos(ang), (float)sin(ang));
}

// ===================== proj_w -> bf16, pad 1440 -> 1536 rows =====================
__global__ void k_wconv(const float* __restrict__ pw, u16* __restrict__ wb) {
  size_t idx = (size_t)blockIdx.x * 256 + threadIdx.x;
  int n = (int)(idx >> 11);
  int k = (int)(idx & 2047);
  float v = (n < P2_) ? pw[(size_t)n * L_ + k] : 0.0f;
  wb[idx] = f2bf(v);
}

// ===================== stats phase 1: partial (S,Q) per (b, chunk, c) =====================
__global__ __launch_bounds__(256) void k_stats1(const float* __restrict__ u, float* __restrict__ ps,
                                                float* __restrict__ pq) {
  int blk = blockIdx.x;            // b*TCHUNK + q
  int b = blk >> 4, q = blk & 15;
  int tid = threadIdx.x;
  int c4 = tid & 15, g = tid >> 4; // 16 groups x 8 t-steps
  const float4* u4 = (const float4*)(u + ((size_t)b * L_ + q * 128) * C_);
  float4 s = make_float4(0.f, 0.f, 0.f, 0.f), sq = s;
#pragma unroll
  for (int i = 0; i < 8; ++i) {
    float4 v = u4[(size_t)(g + 16 * i) * 16 + c4];
    s.x += v.x; s.y += v.y; s.z += v.z; s.w += v.w;
    sq.x += v.x * v.x; sq.y += v.y * v.y; sq.z += v.z * v.z; sq.w += v.w * v.w;
  }
  __shared__ float4 sb[16][16], qb[16][16];
  sb[g][c4] = s; qb[g][c4] = sq;
  __syncthreads();
  if (g == 0) {
    float4 S = sb[0][c4], Q = qb[0][c4];
#pragma unroll
    for (int k = 1; k < 16; ++k) {
      float4 a = sb[k][c4], d = qb[k][c4];
      S.x += a.x; S.y += a.y; S.z += a.z; S.w += a.w;
      Q.x += d.x; Q.y += d.y; Q.z += d.z; Q.w += d.w;
    }
    ((float4*)ps)[blk * 16 + c4] = S;
    ((float4*)pq)[blk * 16 + c4] = Q;
  }
}

// ===================== stats phase 2: combine 16 chunks -> mean, std, 1/std =====================
__global__ __launch_bounds__(256) void k_stats2(const float* __restrict__ ps, const float* __restrict__ pq,
                                                float4* __restrict__ mv) {
  int gid = blockIdx.x * 256 + threadIdx.x;   // B_*C_ = 8192
  int b = gid >> 6, c = gid & 63;
  float S = 0.f, Q = 0.f;
#pragma unroll
  for (int q = 0; q < 16; ++q) {
    S += ps[(size_t)(b * 16 + q) * 64 + c];
    Q += pq[(size_t)(b * 16 + q) * 64 + c];
  }
  float mean = S * (1.0f / 2048.0f);
  float var = (Q - S * S * (1.0f / 2048.0f)) * (1.0f / 2047.0f) + 1e-5f;
  float sv = sqrtf(var);
  mv[gid] = make_float4(mean, sv, 1.0f / sv, 0.0f);
}

// ===================== SSM kernels -> kz[j][h] = (K2[h,j], -K[h,j]) =====================
// NOTE: keep libm expf/sincosf — args reach ~4e4 rad; native __sincosf range
// reduction is too sloppy there (round-6 accuracy creep).
__global__ __launch_bounds__(256) void k_ssmk(const float* __restrict__ Cp, const float* __restrict__ ldt,
                                              const float* __restrict__ lAr, const float* __restrict__ Aim,
                                              float2* __restrict__ kz) {
  int gid = blockIdx.x * 256 + threadIdx.x;   // 64*2048
  int h = gid & 2047;
  int j = gid >> 11;
  float dt = expf(ldt[h]);
  float accx = 0.f;
  float Ar0 = 0.f;
  for (int n = 0; n < 64; ++n) {
    float Ar = -expf(lAr[h * 64 + n]);
    float Ai = Aim[h * 64 + n];
    if (n == 0) Ar0 = Ar;
    float dAr = Ar * dt, dAi = Ai * dt;
    float er = expf(dAr);
    float s1, c1; sincosf(dAi, &s1, &c1);
    float emr = er * c1 - 1.0f, emi = er * s1;
    float inv = 1.0f / (Ar * Ar + Ai * Ai);
    float qr = (emr * Ar + emi * Ai) * inv;
    float qi = (emi * Ar - emr * Ai) * inv;
    float cr = Cp[(size_t)(h * 64 + n) * 2];
    float ci = Cp[(size_t)(h * 64 + n) * 2 + 1];
    float ccr = cr * qr - ci * qi;
    float cci = cr * qi + ci * qr;
    float ej = expf(dAr * (float)j);
    float sj, cj; sincosf(dAi * (float)j, &sj, &cj);
    accx += ccr * (ej * cj) - cci * (ej * sj);
  }
  float K = 2.0f * accx;
  float K2 = 2.0f * K * (Ar0 * (float)j * dt);
  kz[(size_t)j * L_ + h] = make_float2(K2, -K);          // pack K2 - i*K
}

// ===================== normalize + pack (un + i*W) as 2xbf16, transposed to [row][t] =====================
__global__ __launch_bounds__(256) void k_packT(const float* __restrict__ u, const float* __restrict__ Wn,
                                               const float* __restrict__ lv, const float4* __restrict__ mv,
                                               u32* __restrict__ zu) {
  int b = blockIdx.x >> 5;
  int t0 = (blockIdx.x & 31) << 6;
  int tid = threadIdx.x;
  float stdn = sqrtf(__expf(lv[0]));
  __shared__ float2 tile[64][65];
  int c = tid & 63, r = tid >> 6;
  float4 m = mv[b * C_ + c];
#pragma unroll
  for (int i = 0; i < 16; ++i) {
    int t = t0 + i * 4 + r;
    size_t idx = ((size_t)b * L_ + t) * C_ + c;
    float uu = (u[idx] - m.x) * m.z;
    float ww = Wn[idx] * stdn;
    tile[i * 4 + r][c] = make_float2(uu, ww);
  }
  __syncthreads();
  int t = tid & 63, cb = tid >> 6;
#pragma unroll
  for (int i = 0; i < 16; ++i) {
    int c2 = i * 4 + cb;
    float2 v = tile[t][c2];
    zu[((size_t)(b * C_ + c2)) * L_ + t0 + t] = ((u32)f2bf(v.y) << 16) | (u32)f2bf(v.x);
  }
}

// ===================== kernel spectra: G[j] = FFT(K2 - iK)/4096 =====================
__global__ __launch_bounds__(256) void k_fftk(const float2* __restrict__ kz, const float2* __restrict__ twg,
                                              float2* __restrict__ G) {
  __shared__ float2 X[NFFT];
  int j = blockIdx.x, tid = threadIdx.x;
  float2 r[16];
#pragma unroll
  for (int n2 = 0; n2 < 8; ++n2) r[n2] = kz[(size_t)j * L_ + n2 * 256 + tid];
  fft_fwd_hz(r, X, tid, twg);
  const float sc = 1.0f / 4096.0f;
#pragma unroll
  for (int k0 = 0; k0 < 16; ++k0)
    G[(size_t)j * NFFT + k0 * 256 + tid] = make_float2(r[k0].x * sc, r[k0].y * sc);
}

// ===================== main conv per row: y = Re(IFFT(FFT(z) .* G)) + un*D =====================
__global__ __launch_bounds__(256) void k_fftmain(const u32* __restrict__ zu, const float2* __restrict__ twg,
                                                 const float2* __restrict__ G, const float* __restrict__ Dv,
                                                 u16* __restrict__ yT) {
  __shared__ float2 X[NFFT];
  int row = blockIdx.x;           // b*64 + j
  int j = row & 63;
  int tid = threadIdx.x;
  float2 r[16];
  float usav[8];
#pragma unroll
  for (int n2 = 0; n2 < 8; ++n2) {
    u32 v = zu[(size_t)row * L_ + n2 * 256 + tid];
    float uu = bf2f_lo(v), ww = bf2f_hi(v);
    r[n2] = make_float2(uu, ww);
    usav[n2] = uu;
  }
  fft_fwd_hz(r, X, tid, twg);
  const float2* Gj = G + (size_t)j * NFFT;
#pragma unroll
  for (int k0 = 0; k0 < 16; ++k0) r[k0] = cmul(r[k0], Gj[k0 * 256 + tid]);
  fft_inv(r, X, tid, twg);
#pragma unroll
  for (int n2 = 8; n2 < 16; ++n2) {
    int t = (n2 - 8) * 256 + tid;
    float yv = r[n2].x + usav[n2 - 8] * Dv[t];
    yT[(size_t)row * L_ + t] = f2bf(yv);
  }
}

// ===================== bf16 MFMA GEMM — reg-prefetch (stable, round-3 structure) =====================
// z[M=8192][N=1536] = yT[M][K=2048] * Wb[N][K]^T
__global__ __launch_bounds__(256) void k_gemm(const u16* __restrict__ A, const u16* __restrict__ B,
                                              float* __restrict__ Cmat) {
  __shared__ u16 As[128 * 32];
  __shared__ u16 Bs[128 * 32];
  const int K = L_, N = NPAD;
  int tid = threadIdx.x;
  // bijective XCD swizzle: 768 blocks, 96 per XCD
  int bid = blockIdx.x;
  int swz = (bid & 7) * 96 + (bid >> 3);
  int bm = swz % 64, bn = swz / 64;
  int wave = tid >> 6, lane = tid & 63;
  int wm = (wave >> 1) << 6, wn = (wave & 1) << 6;
  int lr = lane & 15, lk = lane >> 4;
  int trow = tid >> 2, tk = (tid & 3) << 3;
  const u16* Ag = A + (size_t)(bm * 128 + trow) * K + tk;
  const u16* Bg = B + (size_t)(bn * 128 + trow) * K + tk;
  f32x4 acc[4][4] = {};
  uint4 pa0 = *(const uint4*)(Ag);
  uint4 pa1 = *(const uint4*)(Ag + (size_t)64 * K);
  uint4 pb0 = *(const uint4*)(Bg);
  uint4 pb1 = *(const uint4*)(Bg + (size_t)64 * K);
  for (int kt = 0; kt < K; kt += 32) {
    __syncthreads();
    *(uint4*)&As[trow * 32 + tk] = pa0;
    *(uint4*)&As[(trow + 64) * 32 + tk] = pa1;
    *(uint4*)&Bs[trow * 32 + tk] = pb0;
    *(uint4*)&Bs[(trow + 64) * 32 + tk] = pb1;
    __syncthreads();
    if (kt + 32 < K) {
      pa0 = *(const uint4*)(Ag + kt + 32);
      pa1 = *(const uint4*)(Ag + (size_t)64 * K + kt + 32);
      pb0 = *(const uint4*)(Bg + kt + 32);
      pb1 = *(const uint4*)(Bg + (size_t)64 * K + kt + 32);
    }
    short8 af[4], bf[4];
#pragma unroll
    for (int i2 = 0; i2 < 4; ++i2) af[i2] = *(const short8*)&As[(wm + i2 * 16 + lr) * 32 + lk * 8];
#pragma unroll
    for (int j2 = 0; j2 < 4; ++j2) bf[j2] = *(const short8*)&Bs[(wn + j2 * 16 + lr) * 32 + lk * 8];
#pragma unroll
    for (int i2 = 0; i2 < 4; ++i2)
#pragma unroll
      for (int j2 = 0; j2 < 4; ++j2)
        acc[i2][j2] = __builtin_amdgcn_mfma_f32_16x16x32_bf16(af[i2], bf[j2], acc[i2][j2], 0, 0, 0);
  }
#pragma unroll
  for (int i2 = 0; i2 < 4; ++i2)
#pragma unroll
    for (int j2 = 0; j2 < 4; ++j2)
#pragma unroll
      for (int r = 0; r < 4; ++r)
        Cmat[(size_t)(bm * 128 + wm + i2 * 16 + lk * 4 + r) * N + bn * 128 + wn + j2 * 16 + lr] =
            acc[i2][j2][r];
}

// ===================== GLU + denorm + transpose to out[b][p][c] =====================
__global__ __launch_bounds__(256) void k_epi(const float* __restrict__ z, const float* __restrict__ pb,
                                             const float4* __restrict__ mv, float* __restrict__ out) {
  int b = blockIdx.x / 23;
  int p0 = (blockIdx.x % 23) * 32;
  int tid = threadIdx.x;
  __shared__ float tile[64][33];
  int pp = tid & 31, ci = tid >> 5;
  for (int cc = ci; cc < 64; cc += 8) {
    int p = p0 + pp;
    float val = 0.f;
    if (p < P_) {
      size_t rowb = (size_t)(b * C_ + cc) * NPAD;
      float a = z[rowb + p] + pb[p];
      float g = z[rowb + P_ + p] + pb[P_ + p];
      float4 m = mv[b * C_ + cc];
      val = a * (1.0f / (1.0f + __expf(-g))) * m.y + m.x;
    }
    tile[cc][pp] = val;
  }
  __syncthreads();
  int c2 = tid & 63, pi = tid >> 6;
  for (int q = pi; q < 32; q += 4) {
    int p = p0 + q;
    if (p < P_) out[((size_t)b * P_ + p) * C_ + c2] = tile[c2][q];
  }
}

extern "C" void kernel_launch(void* const* d_in, const int* in_sizes, int n_in,
                              void* d_out, int out_size, void* d_ws, size_t ws_size,
                              hipStream_t stream) {
  const float* u   = (const float*)d_in[0];
  const float* Wn  = (const float*)d_in[4];
  const float* Dv  = (const float*)d_in[5];
  const float* lv  = (const float*)d_in[6];
  const float* Cp  = (const float*)d_in[7];
  const float* ldt = (const float*)d_in[8];
  const float* lAr = (const float*)d_in[9];
  const float* Aim = (const float*)d_in[10];
  const float* pw  = (const float*)d_in[11];
  const float* pb  = (const float*)d_in[12];
  float* out = (float*)d_out;
  char* ws = (char*)d_ws;

  // workspace layout (bytes)
  float2* tw = (float2*)(ws + 0);                  // 2 KB
  float4* mv = (float4*)(ws + (64 << 10));         // 128 KB  -> ends 192 KB
  float2* G  = (float2*)(ws + (1 << 20));          // 2 MB    -> ends 3 MB
  float2* kz = (float2*)(ws + (3 << 20));          // 1 MB    -> ends 4 MB
  u16*    Wb = (u16*)   (ws + (4 << 20));          // 6 MB    -> ends 10 MB
  float*  ps = (float*) (ws + (10 << 20));         // 512 KB
  float*  pq = (float*) (ws + (10 << 20) + (512 << 10)); // 512 KB -> ends 11 MB
  u16*    yT = (u16*)   (ws + (16 << 20));         // 32 MB   -> ends 48 MB
  u32*    zu = (u32*)   (ws + ((size_t)48 << 20)); // 64 MB   -> ends 112 MB
  float*  zz = (float*) (ws + ((size_t)112 << 20)); // 48 MB  -> ends 160 MB

  k_twfill<<<1, 256, 0, stream>>>(tw);
  k_wconv<<<(NPAD * L_) / 256, 256, 0, stream>>>(pw, Wb);
  k_stats1<<<B_ * TCHUNK, 256, 0, stream>>>(u, ps, pq);
  k_stats2<<<(B_ * C_) / 256, 256, 0, stream>>>(ps, pq, mv);
  k_ssmk<<<(C_ * L_) / 256, 256, 0, stream>>>(Cp, ldt, lAr, Aim, kz);
  k_packT<<<B_ * (L_ / 64), 256, 0, stream>>>(u, Wn, lv, mv, zu);
  k_fftk<<<C_, 256, 0, stream>>>(kz, tw, G);
  k_fftmain<<<NROW, 256, 0, stream>>>(zu, tw, G, Dv, yT);
  k_gemm<<<64 * (NPAD / 128), 256, 0, stream>>>(yT, Wb, zz);
  k_epi<<<B_ * 23, 256, 0, stream>>>(zz, pb, mv, out);
}